// Round 1
// baseline (36374.982 us; speedup 1.0000x reference)
//
#include <hip/hip_runtime.h>
#include <math.h>

// Problem constants (derived from in_sizes at launch for robustness, but the
// reference fixes DIM=768, HID=1536, BATCH=2048, T=32).

#define TILE_BM 64
#define TILE_BN 64
#define TILE_BK 16

// C = epilogue(A @ B + bias).  A: MxK row-major, B: KxN row-major.
// EPI 0: C  = tanh(acc + bias)          (dynamics hidden layer / memory net)
// EPI 1: C += acc + bias                (second dynamics GEMM accumulated onto mem term)
template <int EPI>
__global__ __launch_bounds__(256) void gemm_f32_kernel(
    const float* __restrict__ A, const float* __restrict__ B,
    const float* __restrict__ bias, float* __restrict__ C,
    int M, int N, int K) {
  __shared__ float As[TILE_BK][TILE_BM + 1];
  __shared__ float Bs[TILE_BK][TILE_BN + 1];

  const int tx = threadIdx.x;            // 0..15
  const int ty = threadIdx.y;            // 0..15
  const int tid = ty * 16 + tx;          // 0..255
  const int bm = blockIdx.y * TILE_BM;
  const int bn = blockIdx.x * TILE_BN;

  const int arow = tid >> 4;             // 0..15 (A tile row group)
  const int acol = tid & 15;             // 0..15 (A tile k index)
  const int brow = tid >> 6;             // 0..3  (B tile k group)
  const int bcol = tid & 63;             // 0..63 (B tile col)

  float acc[4][4] = {};

  for (int k0 = 0; k0 < K; k0 += TILE_BK) {
#pragma unroll
    for (int p = 0; p < 4; ++p) {
      // A staged transposed: As[k][m]
      As[acol][arow + 16 * p] =
          A[(size_t)(bm + arow + 16 * p) * K + (k0 + acol)];
      Bs[brow + 4 * p][bcol] =
          B[(size_t)(k0 + brow + 4 * p) * N + (bn + bcol)];
    }
    __syncthreads();
#pragma unroll
    for (int kk = 0; kk < TILE_BK; ++kk) {
      float a[4], b[4];
#pragma unroll
      for (int i = 0; i < 4; ++i) a[i] = As[kk][ty + 16 * i];
#pragma unroll
      for (int j = 0; j < 4; ++j) b[j] = Bs[kk][tx + 16 * j];
#pragma unroll
      for (int i = 0; i < 4; ++i)
#pragma unroll
        for (int j = 0; j < 4; ++j) acc[i][j] += a[i] * b[j];
    }
    __syncthreads();
  }

#pragma unroll
  for (int i = 0; i < 4; ++i) {
    const int row = bm + ty + 16 * i;
#pragma unroll
    for (int j = 0; j < 4; ++j) {
      const int col = bn + tx + 16 * j;
      const float v = acc[i][j] + bias[col];
      size_t idx = (size_t)row * N + col;
      if (EPI == 0)
        C[idx] = tanhf(v);
      else
        C[idx] += v;
    }
  }
}

// y init + first trajectory row: y = x; out[0] = x.
__global__ __launch_bounds__(256) void init_copy_kernel(
    const float* __restrict__ x, float* __restrict__ y,
    float* __restrict__ out0, size_t n) {
  size_t i = (size_t)blockIdx.x * blockDim.x + threadIdx.x;
  if (i < n) {
    float v = x[i];
    y[i] = v;
    out0[i] = v;
  }
}

// RK4 intermediate stage:
//   acc = k          (init==1)    or acc += 2*k   (init==0)
//   ytmp = y + (hmul*h)*k,   h = t[i+1]-t[i] read on device.
__global__ __launch_bounds__(256) void rk_stage_kernel(
    const float* __restrict__ y, const float* __restrict__ k,
    float* __restrict__ acc, float* __restrict__ ytmp,
    const float* __restrict__ tgrid, int step, float hmul, int init,
    size_t n) {
  size_t i = (size_t)blockIdx.x * blockDim.x + threadIdx.x;
  if (i >= n) return;
  const float h = tgrid[step + 1] - tgrid[step];
  const float kv = k[i];
  acc[i] = init ? kv : acc[i] + 2.0f * kv;
  ytmp[i] = y[i] + (hmul * h) * kv;
}

// RK4 final combine: y += (h/6)*(acc + k4); out_row = y.
__global__ __launch_bounds__(256) void rk_final_kernel(
    float* __restrict__ y, const float* __restrict__ k,
    const float* __restrict__ acc, float* __restrict__ out_row,
    const float* __restrict__ tgrid, int step, size_t n) {
  size_t i = (size_t)blockIdx.x * blockDim.x + threadIdx.x;
  if (i >= n) return;
  const float h = tgrid[step + 1] - tgrid[step];
  const float v = y[i] + (h * (1.0f / 6.0f)) * (acc[i] + k[i]);
  y[i] = v;
  out_row[i] = v;
}

static inline void launch_gemm_tanh(const float* A, const float* B,
                                    const float* bias, float* C, int M, int N,
                                    int K, hipStream_t stream) {
  dim3 grid(N / TILE_BN, M / TILE_BM);
  dim3 block(16, 16);
  gemm_f32_kernel<0><<<grid, block, 0, stream>>>(A, B, bias, C, M, N, K);
}

static inline void launch_gemm_acc(const float* A, const float* B,
                                   const float* bias, float* C, int M, int N,
                                   int K, hipStream_t stream) {
  dim3 grid(N / TILE_BN, M / TILE_BM);
  dim3 block(16, 16);
  gemm_f32_kernel<1><<<grid, block, 0, stream>>>(A, B, bias, C, M, N, K);
}

extern "C" void kernel_launch(void* const* d_in, const int* in_sizes, int n_in,
                              void* d_out, int out_size, void* d_ws,
                              size_t ws_size, hipStream_t stream) {
  const float* x  = (const float*)d_in[0];
  const float* t  = (const float*)d_in[1];
  const float* W1 = (const float*)d_in[2];
  const float* b1 = (const float*)d_in[3];
  const float* W2 = (const float*)d_in[4];
  const float* b2 = (const float*)d_in[5];
  const float* Wm = (const float*)d_in[6];
  const float* bm = (const float*)d_in[7];
  float* out = (float*)d_out;

  const int T = in_sizes[1];          // 32
  const int dim = in_sizes[7];        // 768 (bm)
  const int hid = in_sizes[3];        // 1536 (b1)
  const int batch = in_sizes[0] / dim;  // 2048

  const size_t n = (size_t)batch * dim;

  // Workspace partition (floats): y, ytmp, k, acc (n each) + H (batch*hid).
  float* ws = (float*)d_ws;
  float* y    = ws;
  float* ytmp = y + n;
  float* kbuf = ytmp + n;
  float* accb = kbuf + n;
  float* H    = accb + n;  // batch*hid

  const int EB = 256;
  const int egrid = (int)((n + EB - 1) / EB);

  // out[0] = x ; y = x
  init_copy_kernel<<<egrid, EB, 0, stream>>>(x, y, out, n);

  // f(in) -> kout :  kout = tanh(in@Wm+bm) + (tanh(in@W1+b1)@W2 + b2)
  auto feval = [&](const float* in, float* kout) {
    launch_gemm_tanh(in, W1, b1, H, batch, hid, dim, stream);
    launch_gemm_tanh(in, Wm, bm, kout, batch, dim, dim, stream);
    launch_gemm_acc(H, W2, b2, kout, batch, dim, hid, stream);
  };

  for (int i = 0; i < T - 1; ++i) {
    // k1
    feval(y, kbuf);
    rk_stage_kernel<<<egrid, EB, 0, stream>>>(y, kbuf, accb, ytmp, t, i, 0.5f,
                                              1, n);
    // k2
    feval(ytmp, kbuf);
    rk_stage_kernel<<<egrid, EB, 0, stream>>>(y, kbuf, accb, ytmp, t, i, 0.5f,
                                              0, n);
    // k3
    feval(ytmp, kbuf);
    rk_stage_kernel<<<egrid, EB, 0, stream>>>(y, kbuf, accb, ytmp, t, i, 1.0f,
                                              0, n);
    // k4 + combine
    feval(ytmp, kbuf);
    rk_final_kernel<<<egrid, EB, 0, stream>>>(y, kbuf, accb,
                                              out + (size_t)(i + 1) * n, t, i,
                                              n);
  }
}

// Round 2
// 7679.797 us; speedup vs baseline: 4.7365x; 4.7365x over previous
//
#include <hip/hip_runtime.h>
#include <math.h>

// Problem constants (fixed by the reference).
#define DIM   768
#define HID   1536
#define NCAT  2304            // HID + DIM (W1 | Wm concatenated on output dim)
#define BATCH 2048
#define NELEM (BATCH * DIM)   // 1572864
#define MN    NELEM

typedef short s16x8 __attribute__((ext_vector_type(8)));
typedef float f32x4 __attribute__((ext_vector_type(4)));
typedef unsigned short u16x4 __attribute__((ext_vector_type(4)));

// ---------- small numeric helpers ----------
__device__ __forceinline__ unsigned short f2bf(float f) {
  // RNE float -> bf16 bits
  unsigned int u = __builtin_bit_cast(unsigned int, f);
  u = (u + 0x7FFFu + ((u >> 16) & 1u)) >> 16;
  return (unsigned short)u;
}
__device__ __forceinline__ float bf2f(unsigned short b) {
  unsigned int u = ((unsigned int)b) << 16;
  return __builtin_bit_cast(float, u);
}
__device__ __forceinline__ float fast_tanh(float x) {
  // exact identity tanh(x) = 1 - 2/(exp(2x)+1); __expf ~2^-21 rel err.
  float e = __expf(2.0f * x);
  return 1.0f - 2.0f / (e + 1.0f);
}

// ---------- async global->LDS staging ----------
#define AS1 __attribute__((address_space(1)))
#define AS3 __attribute__((address_space(3)))
__device__ __forceinline__ void gload_lds16(const void* g, void* l) {
  __builtin_amdgcn_global_load_lds((const AS1 unsigned int*)g,
                                   (AS3 unsigned int*)l, 16, 0, 0);
}

// Stage one 128x32 bf16 tile (8 KiB) from row-major [rows][K] global memory.
// LDS layout is linear [row][32] bf16 (64 B rows), but the 16B slot index is
// XOR-swizzled with ((row>>1)&3) via the GLOBAL source address (rule: linear
// dest + inverse-swizzled source + swizzled read).
__device__ __forceinline__ void stage_tile(const unsigned short* __restrict__ g,
                                           int K, char* lds_base, int w, int l) {
#pragma unroll
  for (int jj = 0; jj < 2; ++jj) {
    const int j = w + jj * 4;              // chunk 0..7, wave-uniform
    const int row = j * 16 + (l >> 2);     // tile row 0..127
    const int slot = (l & 3) ^ ((row >> 1) & 3);
    gload_lds16(g + (size_t)row * K + slot * 8, lds_base + j * 1024);
  }
}

// Swizzled 16B fragment read: row-local tile row, q = k-half (l>>4).
__device__ __forceinline__ s16x8 ldfrag(const char* base, int row, int q) {
  const int slot = q ^ ((row >> 1) & 3);
  return *reinterpret_cast<const s16x8*>(base + row * 64 + slot * 16);
}

// ---------- MFMA GEMM ----------
// C[M x N] = A[M x K] @ B^T[N x K]^T, bf16 inputs, fp32 accum.
// MODE 0 (fused state GEMM): A split hi/lo (2 MFMA passes), N = NCAT.
//        epilogue t = tanh(acc + bias): cols < HID -> Hh (bf16), else kmem fp32.
// MODE 1 (dyn GEMM3): A = Hh single-pass, K = HID, split-K via blockIdx.z;
//        epilogue writes raw fp32 partial to Fout + z*MN.
template <int MODE>
__global__ __launch_bounds__(256, 3) void gemm_mfma_kernel(
    const unsigned short* __restrict__ Ah, const unsigned short* __restrict__ Al,
    const unsigned short* __restrict__ Bt, const float* __restrict__ bias,
    unsigned short* __restrict__ Hout, float* __restrict__ Fout,
    int K, int ksub) {
  __shared__ __align__(16) char smem[(MODE == 0 ? 3 : 2) * 8192];

  const int tid = threadIdx.x;
  const int w = tid >> 6, l = tid & 63;
  const int lr = l & 15, lq = l >> 4;
  const int m0 = blockIdx.y * 128;
  const int n0 = blockIdx.x * 128;
  const int wr = (w >> 1) * 64;   // wave row offset in tile
  const int wc = (w & 1) * 64;    // wave col offset in tile
  const int k0 = blockIdx.z * ksub;
  const int kiters = ksub / 32;

  const unsigned short* Ag  = Ah + (size_t)m0 * K + k0;
  const unsigned short* Bg  = Bt + (size_t)n0 * K + k0;
  const unsigned short* Alg = (MODE == 0) ? (Al + (size_t)m0 * K + k0) : nullptr;

  f32x4 acc[4][4];
#pragma unroll
  for (int m = 0; m < 4; ++m)
#pragma unroll
    for (int n = 0; n < 4; ++n) acc[m][n] = f32x4{0.f, 0.f, 0.f, 0.f};

  char* As  = smem;
  char* Bs  = smem + 8192;
  char* Als = smem + 16384;  // MODE 0 only

  for (int kt = 0; kt < kiters; ++kt) {
    stage_tile(Ag, K, As, w, l);
    stage_tile(Bg, K, Bs, w, l);
    if (MODE == 0) stage_tile(Alg, K, Als, w, l);
    Ag += 32; Bg += 32;
    if (MODE == 0) Alg += 32;
    asm volatile("s_waitcnt vmcnt(0)" ::: "memory");
    __syncthreads();

    s16x8 bfr[4], afr[4], alfr[4];
#pragma unroll
    for (int n = 0; n < 4; ++n) bfr[n] = ldfrag(Bs, wc + n * 16 + lr, lq);
#pragma unroll
    for (int m = 0; m < 4; ++m) afr[m] = ldfrag(As, wr + m * 16 + lr, lq);
    if (MODE == 0) {
#pragma unroll
      for (int m = 0; m < 4; ++m) alfr[m] = ldfrag(Als, wr + m * 16 + lr, lq);
    }

#pragma unroll
    for (int m = 0; m < 4; ++m)
#pragma unroll
      for (int n = 0; n < 4; ++n) {
        acc[m][n] = __builtin_amdgcn_mfma_f32_16x16x32_bf16(afr[m], bfr[n],
                                                            acc[m][n], 0, 0, 0);
        if (MODE == 0)
          acc[m][n] = __builtin_amdgcn_mfma_f32_16x16x32_bf16(alfr[m], bfr[n],
                                                              acc[m][n], 0, 0, 0);
      }
    __syncthreads();
  }

  // Epilogue. C/D layout (m89-verified): col = lane&15, row = (lane>>4)*4 + j.
  float* Fz = (MODE == 1) ? (Fout + (size_t)blockIdx.z * MN) : Fout;
#pragma unroll
  for (int m = 0; m < 4; ++m) {
#pragma unroll
    for (int n = 0; n < 4; ++n) {
      const int gcol = n0 + wc + n * 16 + lr;
      const float bv = (MODE == 0) ? bias[gcol] : 0.0f;
#pragma unroll
      for (int j = 0; j < 4; ++j) {
        const int grow = m0 + wr + m * 16 + lq * 4 + j;
        const float v = acc[m][n][j] + bv;
        if (MODE == 0) {
          const float t = fast_tanh(v);
          if (n0 < HID) {
            Hout[(size_t)grow * HID + gcol] = f2bf(t);
          } else {
            Fz[(size_t)grow * DIM + (gcol - HID)] = t;
          }
        } else {
          Fz[(size_t)grow * DIM + gcol] = v;
        }
      }
    }
  }
}

// ---------- elementwise kernels ----------
__global__ __launch_bounds__(256) void init_k(
    const float* __restrict__ x, float* __restrict__ y, float* __restrict__ out0,
    unsigned short* __restrict__ yh, unsigned short* __restrict__ yl) {
  const int i4 = blockIdx.x * 256 + threadIdx.x;
  const int base = i4 * 4;
  f32x4 v = *(const f32x4*)(x + base);
  *(f32x4*)(y + base) = v;
  *(f32x4*)(out0 + base) = v;
  u16x4 hb, lb;
#pragma unroll
  for (int j = 0; j < 4; ++j) {
    unsigned short h = f2bf(v[j]);
    hb[j] = h;
    lb[j] = f2bf(v[j] - bf2f(h));
  }
  *(u16x4*)(yh + base) = hb;
  *(u16x4*)(yl + base) = lb;
}

// kv = kmem + kp0 + kp1 + b2;  acc = init? kv : acc + 2kv;  t = y + c*h*kv
__global__ __launch_bounds__(256) void rk_stage_k(
    const float* __restrict__ y, const float* __restrict__ kmem,
    const float* __restrict__ kp0, const float* __restrict__ kp1,
    const float* __restrict__ b2, float* __restrict__ accb,
    float* __restrict__ ytmp, unsigned short* __restrict__ th,
    unsigned short* __restrict__ tl, const float* __restrict__ tg, int step,
    float hmul, int initf) {
  const int i4 = blockIdx.x * 256 + threadIdx.x;
  const int base = i4 * 4;
  const float h = tg[step + 1] - tg[step];
  f32x4 kv = *(const f32x4*)(kmem + base);
  kv += *(const f32x4*)(kp0 + base);
  kv += *(const f32x4*)(kp1 + base);
  kv += *(const f32x4*)(b2 + (base % DIM));
  f32x4 av = initf ? kv : (*(const f32x4*)(accb + base) + 2.0f * kv);
  *(f32x4*)(accb + base) = av;
  f32x4 tv = *(const f32x4*)(y + base) + (hmul * h) * kv;
  *(f32x4*)(ytmp + base) = tv;
  u16x4 hb, lb;
#pragma unroll
  for (int j = 0; j < 4; ++j) {
    unsigned short hx = f2bf(tv[j]);
    hb[j] = hx;
    lb[j] = f2bf(tv[j] - bf2f(hx));
  }
  *(u16x4*)(th + base) = hb;
  *(u16x4*)(tl + base) = lb;
}

// y += h/6 * (accb + kv); out_row = y; re-split y.
__global__ __launch_bounds__(256) void rk_final_k(
    float* __restrict__ y, const float* __restrict__ kmem,
    const float* __restrict__ kp0, const float* __restrict__ kp1,
    const float* __restrict__ b2, const float* __restrict__ accb,
    float* __restrict__ out_row, unsigned short* __restrict__ yh,
    unsigned short* __restrict__ yl, const float* __restrict__ tg, int step) {
  const int i4 = blockIdx.x * 256 + threadIdx.x;
  const int base = i4 * 4;
  const float h = tg[step + 1] - tg[step];
  f32x4 kv = *(const f32x4*)(kmem + base);
  kv += *(const f32x4*)(kp0 + base);
  kv += *(const f32x4*)(kp1 + base);
  kv += *(const f32x4*)(b2 + (base % DIM));
  f32x4 v = *(const f32x4*)(y + base) +
            (h * (1.0f / 6.0f)) * (*(const f32x4*)(accb + base) + kv);
  *(f32x4*)(y + base) = v;
  *(f32x4*)(out_row + base) = v;
  u16x4 hb, lb;
#pragma unroll
  for (int j = 0; j < 4; ++j) {
    unsigned short hx = f2bf(v[j]);
    hb[j] = hx;
    lb[j] = f2bf(v[j] - bf2f(hx));
  }
  *(u16x4*)(yh + base) = hb;
  *(u16x4*)(yl + base) = lb;
}

// ---------- per-launch weight prep (transpose + bf16 cast) ----------
__global__ __launch_bounds__(256) void prep_wcat_k(
    const float* __restrict__ W1, const float* __restrict__ Wm,
    unsigned short* __restrict__ out) {  // [NCAT][DIM] = concat(W1^T, Wm^T)
  const int idx = blockIdx.x * 256 + threadIdx.x;  // NCAT*DIM threads
  const int nrow = idx / DIM, k = idx % DIM;
  const float v = (nrow < HID) ? W1[(size_t)k * HID + nrow]
                               : Wm[(size_t)k * DIM + (nrow - HID)];
  out[idx] = f2bf(v);
}
__global__ __launch_bounds__(256) void prep_w2t_k(
    const float* __restrict__ W2, unsigned short* __restrict__ out) {  // [DIM][HID]
  const int idx = blockIdx.x * 256 + threadIdx.x;  // DIM*HID threads
  const int nrow = idx / HID, k = idx % HID;
  out[idx] = f2bf(W2[(size_t)k * DIM + nrow]);
}
__global__ __launch_bounds__(256) void prep_bias_k(
    const float* __restrict__ b1, const float* __restrict__ bmv,
    float* __restrict__ out) {  // [NCAT]
  const int i = blockIdx.x * 256 + threadIdx.x;
  if (i < NCAT) out[i] = (i < HID) ? b1[i] : bmv[i - HID];
}

extern "C" void kernel_launch(void* const* d_in, const int* in_sizes, int n_in,
                              void* d_out, int out_size, void* d_ws,
                              size_t ws_size, hipStream_t stream) {
  const float* x  = (const float*)d_in[0];
  const float* tg = (const float*)d_in[1];
  const float* W1 = (const float*)d_in[2];
  const float* b1 = (const float*)d_in[3];
  const float* W2 = (const float*)d_in[4];
  const float* b2 = (const float*)d_in[5];
  const float* Wm = (const float*)d_in[6];
  const float* bm = (const float*)d_in[7];
  float* out = (float*)d_out;
  const int T = in_sizes[1];  // 32

  // ---- workspace partition (~62.5 MB) ----
  float* y        = (float*)d_ws;          // NELEM
  float* ytmp     = y + NELEM;
  float* kmem     = ytmp + NELEM;          // mem-term (fused GEMM fp32 out)
  float* accb     = kmem + NELEM;
  float* kpart    = accb + NELEM;          // 2 * NELEM (split-K partials)
  float* bias_cat = kpart + 2 * (size_t)NELEM;  // NCAT
  unsigned short* yh    = (unsigned short*)(bias_cat + NCAT);
  unsigned short* yl    = yh + NELEM;
  unsigned short* th    = yl + NELEM;
  unsigned short* tl    = th + NELEM;
  unsigned short* Hh    = tl + NELEM;            // BATCH*HID
  unsigned short* WcatT = Hh + (size_t)BATCH * HID;  // NCAT*DIM
  unsigned short* W2T   = WcatT + (size_t)NCAT * DIM; // DIM*HID
  float* kp0 = kpart;
  float* kp1 = kpart + NELEM;

  // ---- per-launch prep ----
  prep_wcat_k<<<(NCAT * DIM) / 256, 256, 0, stream>>>(W1, Wm, WcatT);
  prep_w2t_k<<<(DIM * HID) / 256, 256, 0, stream>>>(W2, W2T);
  prep_bias_k<<<(NCAT + 255) / 256, 256, 0, stream>>>(b1, bm, bias_cat);

  const int egrid = NELEM / 4 / 256;  // 1536
  init_k<<<egrid, 256, 0, stream>>>(x, y, out, yh, yl);

  // f(in_h, in_l): fused state GEMM -> Hh + kmem; then GEMM3 -> kp0, kp1.
  auto feval = [&](const unsigned short* ah, const unsigned short* al) {
    gemm_mfma_kernel<0><<<dim3(NCAT / 128, BATCH / 128, 1), 256, 0, stream>>>(
        ah, al, WcatT, bias_cat, Hh, kmem, DIM, DIM);
    gemm_mfma_kernel<1><<<dim3(DIM / 128, BATCH / 128, 2), 256, 0, stream>>>(
        Hh, nullptr, W2T, nullptr, nullptr, kpart, HID, HID / 2);
  };

  for (int i = 0; i < T - 1; ++i) {
    // k1 (from y)
    feval(yh, yl);
    rk_stage_k<<<egrid, 256, 0, stream>>>(y, kmem, kp0, kp1, b2, accb, ytmp, th,
                                          tl, tg, i, 0.5f, 1);
    // k2
    feval(th, tl);
    rk_stage_k<<<egrid, 256, 0, stream>>>(y, kmem, kp0, kp1, b2, accb, ytmp, th,
                                          tl, tg, i, 0.5f, 0);
    // k3
    feval(th, tl);
    rk_stage_k<<<egrid, 256, 0, stream>>>(y, kmem, kp0, kp1, b2, accb, ytmp, th,
                                          tl, tg, i, 1.0f, 0);
    // k4 + combine
    feval(th, tl);
    rk_final_k<<<egrid, 256, 0, stream>>>(y, kmem, kp0, kp1, b2, accb,
                                          out + (size_t)(i + 1) * NELEM, yh, yl,
                                          tg, i);
  }
}

// Round 3
// 7137.766 us; speedup vs baseline: 5.0961x; 1.0759x over previous
//
#include <hip/hip_runtime.h>
#include <math.h>

// Problem constants (fixed by the reference).
#define DIM   768
#define HID   1536
#define NCAT  2304            // HID + DIM (W1 | Wm concatenated on output dim)
#define BATCH 2048
#define NELEM (BATCH * DIM)   // 1572864

typedef short s16x8 __attribute__((ext_vector_type(8)));
typedef float f32x4 __attribute__((ext_vector_type(4)));
typedef unsigned short u16x4 __attribute__((ext_vector_type(4)));

// ---------- numeric helpers ----------
__device__ __forceinline__ unsigned short f2bf(float f) {
  unsigned int u = __builtin_bit_cast(unsigned int, f);
  u = (u + 0x7FFFu + ((u >> 16) & 1u)) >> 16;
  return (unsigned short)u;
}
__device__ __forceinline__ float bf2f(unsigned short b) {
  unsigned int u = ((unsigned int)b) << 16;
  return __builtin_bit_cast(float, u);
}
__device__ __forceinline__ float fast_tanh(float x) {
  float e = __expf(2.0f * x);
  return 1.0f - 2.0f / (e + 1.0f);
}

// ---------- async global->LDS staging ----------
#define AS1 __attribute__((address_space(1)))
#define AS3 __attribute__((address_space(3)))
__device__ __forceinline__ void gload_lds16(const void* g, void* l) {
  __builtin_amdgcn_global_load_lds((const AS1 unsigned int*)g,
                                   (AS3 unsigned int*)l, 16, 0, 0);
}

// Stage a ROWSx32 bf16 tile from row-major [.][K] global into LDS (64B rows,
// linear dest). 16B slot index XOR-swizzled via the GLOBAL source address
// (linear dest + inverse-swizzled source + swizzled read; rule #21).
template <int ROWS>
__device__ __forceinline__ void stage_tile(const unsigned short* __restrict__ g,
                                           int K, char* lds, int w, int l) {
  constexpr int NCH = ROWS / 16;  // 16-row chunks of 1 KiB
#pragma unroll
  for (int jj = 0; jj < (NCH + 3) / 4; ++jj) {
    const int j = w + jj * 4;  // wave-uniform chunk id
    if (NCH % 4 == 0 || j < NCH) {
      const int row = j * 16 + (l >> 2);
      const int slot = (l & 3) ^ ((row >> 1) & 3);
      gload_lds16(g + (size_t)row * K + slot * 8, lds + j * 1024);
    }
  }
}

// Swizzled 16B fragment read: tile row, q = k-quarter (lane>>4).
__device__ __forceinline__ s16x8 ldfrag(const char* base, int row, int q) {
  const int slot = q ^ ((row >> 1) & 3);
  return *reinterpret_cast<const s16x8*>(base + row * 64 + slot * 16);
}

// ---------- fused MFMA GEMM ----------
// Tile 64(M) x 96(N), 4 waves (wave-tile 32x48), BK=32.
// MODE 0: state GEMM. A = (th|tl) split hi/lo (2 MFMA passes), B = WcatT
//         [NCAT][DIM], epilogue t = tanh(acc+bias): col<HID -> Hh bf16,
//         else kmem fp32 (the memory term).
// MODE 1: dyn GEMM (A = Hh, K = HID) + fused RK STAGE epilogue:
//         kv = acc + kmem + b2; accb = init? kv : accb+2kv;
//         tv = y + hmul*h*kv -> th/tl (split bf16).
// MODE 2: dyn GEMM + fused RK FINAL epilogue:
//         kv = acc + kmem + b2; y += h/6*(accb+kv); out_row = y; yh/yl split.
template <int MODE>
__global__ __launch_bounds__(256, 3) void gemm_k(
    const unsigned short* __restrict__ Ah, const unsigned short* __restrict__ Al,
    const unsigned short* __restrict__ Bt, const float* __restrict__ bias,
    unsigned short* __restrict__ Hout, float* __restrict__ kmem,
    const float* __restrict__ b2, float* __restrict__ y,
    float* __restrict__ accb, unsigned short* __restrict__ th,
    unsigned short* __restrict__ tl, float* __restrict__ out_row,
    const float* __restrict__ tg, int K, int step, float hmul, int initf) {
  __shared__ __align__(16) char smem[(MODE == 0) ? 14336 : 10240];

  const int tid = threadIdx.x;
  const int w = tid >> 6, l = tid & 63;
  const int lr = l & 15, lq = l >> 4;
  const int m0 = blockIdx.y * 64;
  const int n0 = blockIdx.x * 96;
  const int wr = (w >> 1) * 32;
  const int wc = (w & 1) * 48;

  const unsigned short* Ag  = Ah + (size_t)m0 * K;
  const unsigned short* Bg  = Bt + (size_t)n0 * K;
  const unsigned short* Alg = (MODE == 0) ? (Al + (size_t)m0 * K) : nullptr;

  f32x4 acc[2][3];
#pragma unroll
  for (int m = 0; m < 2; ++m)
#pragma unroll
    for (int n = 0; n < 3; ++n) acc[m][n] = f32x4{0.f, 0.f, 0.f, 0.f};

  char* As  = smem;           // 4 KiB (64x32)
  char* Bs  = smem + 4096;    // 6 KiB (96x32)
  char* Als = smem + 10240;   // 4 KiB (MODE 0 only)

  const int kiters = K / 32;
  for (int kt = 0; kt < kiters; ++kt) {
    stage_tile<64>(Ag, K, As, w, l);
    stage_tile<96>(Bg, K, Bs, w, l);
    if (MODE == 0) stage_tile<64>(Alg, K, Als, w, l);
    Ag += 32; Bg += 32;
    if (MODE == 0) Alg += 32;
    asm volatile("s_waitcnt vmcnt(0)" ::: "memory");
    __syncthreads();

    s16x8 bfr[3], afr[2], alfr[2];
#pragma unroll
    for (int n = 0; n < 3; ++n) bfr[n] = ldfrag(Bs, wc + n * 16 + lr, lq);
#pragma unroll
    for (int m = 0; m < 2; ++m) afr[m] = ldfrag(As, wr + m * 16 + lr, lq);
    if (MODE == 0) {
#pragma unroll
      for (int m = 0; m < 2; ++m) alfr[m] = ldfrag(Als, wr + m * 16 + lr, lq);
    }

#pragma unroll
    for (int m = 0; m < 2; ++m)
#pragma unroll
      for (int n = 0; n < 3; ++n) {
        acc[m][n] = __builtin_amdgcn_mfma_f32_16x16x32_bf16(afr[m], bfr[n],
                                                            acc[m][n], 0, 0, 0);
        if (MODE == 0)
          acc[m][n] = __builtin_amdgcn_mfma_f32_16x16x32_bf16(alfr[m], bfr[n],
                                                              acc[m][n], 0, 0, 0);
      }
    __syncthreads();
  }

  // Epilogue. C/D layout (m89-verified): col = lane&15, row = (lane>>4)*4 + j.
  if (MODE == 0) {
#pragma unroll
    for (int m = 0; m < 2; ++m)
#pragma unroll
      for (int n = 0; n < 3; ++n) {
        const int gcol = n0 + wc + n * 16 + lr;
        const float bv = bias[gcol];
#pragma unroll
        for (int j = 0; j < 4; ++j) {
          const int grow = m0 + wr + m * 16 + lq * 4 + j;
          const float t = fast_tanh(acc[m][n][j] + bv);
          if (gcol < HID)
            Hout[(size_t)grow * HID + gcol] = f2bf(t);
          else
            kmem[(size_t)grow * DIM + (gcol - HID)] = t;
        }
      }
  } else {
    const float h = tg[step + 1] - tg[step];
#pragma unroll
    for (int m = 0; m < 2; ++m)
#pragma unroll
      for (int n = 0; n < 3; ++n) {
        const int gcol = n0 + wc + n * 16 + lr;
        const float bv = b2[gcol];
#pragma unroll
        for (int j = 0; j < 4; ++j) {
          const int grow = m0 + wr + m * 16 + lq * 4 + j;
          const size_t idx = (size_t)grow * DIM + gcol;
          const float kv = acc[m][n][j] + kmem[idx] + bv;
          if (MODE == 1) {
            const float av = initf ? kv : (accb[idx] + 2.0f * kv);
            accb[idx] = av;
            const float tv = y[idx] + (hmul * h) * kv;
            const unsigned short hx = f2bf(tv);
            th[idx] = hx;
            tl[idx] = f2bf(tv - bf2f(hx));
          } else {
            const float v = y[idx] + (h * (1.0f / 6.0f)) * (accb[idx] + kv);
            y[idx] = v;
            out_row[idx] = v;
            const unsigned short hx = f2bf(v);
            th[idx] = hx;
            tl[idx] = f2bf(v - bf2f(hx));
          }
        }
      }
  }
}

// ---------- init + weight prep ----------
__global__ __launch_bounds__(256) void init_k(
    const float* __restrict__ x, float* __restrict__ y, float* __restrict__ out0,
    unsigned short* __restrict__ yh, unsigned short* __restrict__ yl) {
  const int i4 = blockIdx.x * 256 + threadIdx.x;
  const int base = i4 * 4;
  f32x4 v = *(const f32x4*)(x + base);
  *(f32x4*)(y + base) = v;
  *(f32x4*)(out0 + base) = v;
  u16x4 hb, lb;
#pragma unroll
  for (int j = 0; j < 4; ++j) {
    unsigned short h = f2bf(v[j]);
    hb[j] = h;
    lb[j] = f2bf(v[j] - bf2f(h));
  }
  *(u16x4*)(yh + base) = hb;
  *(u16x4*)(yl + base) = lb;
}

__global__ __launch_bounds__(256) void prep_wcat_k(
    const float* __restrict__ W1, const float* __restrict__ Wm,
    unsigned short* __restrict__ out) {  // [NCAT][DIM] = concat(W1^T, Wm^T)
  const int idx = blockIdx.x * 256 + threadIdx.x;
  const int nrow = idx / DIM, k = idx % DIM;
  const float v = (nrow < HID) ? W1[(size_t)k * HID + nrow]
                               : Wm[(size_t)k * DIM + (nrow - HID)];
  out[idx] = f2bf(v);
}
__global__ __launch_bounds__(256) void prep_w2t_k(
    const float* __restrict__ W2, unsigned short* __restrict__ out) {  // [DIM][HID]
  const int idx = blockIdx.x * 256 + threadIdx.x;
  const int nrow = idx / HID, k = idx % HID;
  out[idx] = f2bf(W2[(size_t)k * DIM + nrow]);
}
__global__ __launch_bounds__(256) void prep_bias_k(
    const float* __restrict__ b1, const float* __restrict__ bmv,
    float* __restrict__ out) {  // [NCAT]
  const int i = blockIdx.x * 256 + threadIdx.x;
  if (i < NCAT) out[i] = (i < HID) ? b1[i] : bmv[i - HID];
}

extern "C" void kernel_launch(void* const* d_in, const int* in_sizes, int n_in,
                              void* d_out, int out_size, void* d_ws,
                              size_t ws_size, hipStream_t stream) {
  const float* x  = (const float*)d_in[0];
  const float* tg = (const float*)d_in[1];
  const float* W1 = (const float*)d_in[2];
  const float* b1 = (const float*)d_in[3];
  const float* W2 = (const float*)d_in[4];
  const float* b2 = (const float*)d_in[5];
  const float* Wm = (const float*)d_in[6];
  const float* bm = (const float*)d_in[7];
  float* out = (float*)d_out;
  const int T = in_sizes[1];  // 32

  // ---- workspace partition ----
  float* y        = (float*)d_ws;               // NELEM
  float* accb     = y + NELEM;                  // NELEM
  float* kmem     = accb + NELEM;               // NELEM
  float* bias_cat = kmem + NELEM;               // NCAT
  unsigned short* yh    = (unsigned short*)(bias_cat + NCAT);
  unsigned short* yl    = yh + NELEM;
  unsigned short* th    = yl + NELEM;
  unsigned short* tl    = th + NELEM;
  unsigned short* Hh    = tl + NELEM;                 // BATCH*HID
  unsigned short* WcatT = Hh + (size_t)BATCH * HID;   // NCAT*DIM
  unsigned short* W2T   = WcatT + (size_t)NCAT * DIM; // DIM*HID

  // ---- per-launch prep ----
  prep_wcat_k<<<(NCAT * DIM) / 256, 256, 0, stream>>>(W1, Wm, WcatT);
  prep_w2t_k<<<(DIM * HID) / 256, 256, 0, stream>>>(W2, W2T);
  prep_bias_k<<<(NCAT + 255) / 256, 256, 0, stream>>>(b1, bm, bias_cat);
  init_k<<<NELEM / 1024, 256, 0, stream>>>(x, y, out, yh, yl);

  const dim3 g0(NCAT / 96, BATCH / 64);  // 24 x 32 = 768 blocks
  const dim3 g1(DIM / 96, BATCH / 64);   //  8 x 32 = 256 blocks

  auto gemm0 = [&](const unsigned short* ah, const unsigned short* al) {
    gemm_k<0><<<g0, 256, 0, stream>>>(ah, al, WcatT, bias_cat, Hh, kmem,
                                      nullptr, nullptr, nullptr, nullptr,
                                      nullptr, nullptr, nullptr, DIM, 0, 0.f, 0);
  };
  auto gemm1_stage = [&](int step, float hmul, int initf) {
    gemm_k<1><<<g1, 256, 0, stream>>>(Hh, nullptr, W2T, nullptr, nullptr, kmem,
                                      b2, y, accb, th, tl, nullptr, tg, HID,
                                      step, hmul, initf);
  };
  auto gemm1_final = [&](int step, float* orow) {
    gemm_k<2><<<g1, 256, 0, stream>>>(Hh, nullptr, W2T, nullptr, nullptr, kmem,
                                      b2, y, accb, yh, yl, orow, tg, HID,
                                      step, 0.f, 0);
  };

  for (int i = 0; i < T - 1; ++i) {
    gemm0(yh, yl);  gemm1_stage(i, 0.5f, 1);   // k1
    gemm0(th, tl);  gemm1_stage(i, 0.5f, 0);   // k2
    gemm0(th, tl);  gemm1_stage(i, 1.0f, 0);   // k3
    gemm0(th, tl);  gemm1_final(i, out + (size_t)(i + 1) * NELEM);  // k4
  }
}

// Round 4
// 6637.254 us; speedup vs baseline: 5.4804x; 1.0754x over previous
//
#include <hip/hip_runtime.h>
#include <math.h>

// Problem constants (fixed by the reference).
#define DIM   768
#define HID   1536
#define NCAT  2304            // HID + DIM (W1 | Wm concatenated on output dim)
#define BATCH 2048
#define NELEM (BATCH * DIM)   // 1572864

typedef _Float16 f16x8 __attribute__((ext_vector_type(8)));
typedef _Float16 f16x4 __attribute__((ext_vector_type(4)));
typedef float f32x4 __attribute__((ext_vector_type(4)));

// ---------- numeric helpers ----------
__device__ __forceinline__ float fast_tanh(float x) {
  float e = __expf(2.0f * x);
  return 1.0f - 2.0f / (e + 1.0f);
}

// ---------- async global->LDS staging ----------
#define AS1 __attribute__((address_space(1)))
#define AS3 __attribute__((address_space(3)))
__device__ __forceinline__ void gload_lds16(const void* g, void* l) {
  __builtin_amdgcn_global_load_lds((const AS1 unsigned int*)g,
                                   (AS3 unsigned int*)l, 16, 0, 0);
}

// Stage a ROWSx64 fp16 tile (128 B rows) from row-major [.][K] global into
// LDS. Linear LDS dest (global_load_lds requirement); the 16B slot index is
// XOR-swizzled via the GLOBAL source address; reads apply the same swizzle
// (rule #21: linear dest + inverse-swizzled source + swizzled read).
// Each wave-issue covers 8 rows (8 slots x 8 rows = 64 lanes).
template <int ROWS>
__device__ __forceinline__ void stage_tile(const _Float16* __restrict__ g,
                                           int K, char* lds, int w, int l) {
  constexpr int ISS = ROWS / 8;   // total 16B wave-issues for this tile
  const int sub  = l >> 3;        // row within 8-row chunk (== row & 7)
  const int slot = (l & 7) ^ sub; // inverse-swizzled source slot
#pragma unroll
  for (int i = 0; i < ISS / 4; ++i) {
    const int j = w + i * 4;      // chunk id, wave-uniform
    const int row = j * 8 + sub;
    gload_lds16(g + (size_t)row * K + slot * 8, lds + j * 1024);
  }
}

// Swizzled 16B fragment read. kk = k32 sub-block (0/1), lq = lane>>4.
// Bank check: 16 lanes with consecutive rows hit 8 distinct slots twice
// -> 2-way (free).
__device__ __forceinline__ f16x8 ldfrag(const char* base, int row, int kk,
                                        int lq) {
  const int slot = (kk * 4 + lq) ^ (row & 7);
  return *reinterpret_cast<const f16x8*>(base + row * 128 + slot * 16);
}

// ---------- fused MFMA GEMM (fp16 inputs, fp32 accum) ----------
// MODE 0: state GEMM. Tile 128x128, wave-tile 64x64 (acc 4x4), BK=64.
//         A = state fp16 [BATCH][DIM], B = WcatT [NCAT][DIM].
//         Epilogue t = tanh(acc+bias): col<HID -> H fp16, else kmem fp32.
// MODE 1: dyn GEMM (A = H, K = HID) + fused RK STAGE epilogue.
//         Tile 64x96, wave-tile 32x48 (acc 2x3), BK=64, grid 256 = exact fill.
//         kv = acc + kmem + b2; accb = init? kv : accb+2kv;
//         tv = y + hmul*h*kv -> ts fp16.
// MODE 2: dyn GEMM + fused RK FINAL epilogue:
//         kv = acc + kmem + b2; y += h/6*(accb+kv); out_row = y; ts = fp16(y).
template <int MODE>
__global__ __launch_bounds__(256, 3) void gemm_k(
    const _Float16* __restrict__ A, const _Float16* __restrict__ Bt,
    const float* __restrict__ bias, _Float16* __restrict__ Hout,
    float* __restrict__ kmem, const float* __restrict__ b2,
    float* __restrict__ y, float* __restrict__ accb,
    _Float16* __restrict__ ts, float* __restrict__ out_row,
    const float* __restrict__ tg, int K, int step, float hmul, int initf) {
  constexpr int BM = (MODE == 0) ? 128 : 64;
  constexpr int BN = (MODE == 0) ? 128 : 96;
  constexpr int WM = BM / 2 / 16;  // m-frags per wave (4 or 2)
  constexpr int WN = BN / 2 / 16;  // n-frags per wave (4 or 3)
  __shared__ __align__(16) char smem[(BM + BN) * 128];

  const int tid = threadIdx.x;
  const int w = tid >> 6, l = tid & 63;
  const int lr = l & 15, lq = l >> 4;
  const int m0 = blockIdx.y * BM;
  const int n0 = blockIdx.x * BN;
  const int wr = (w >> 1) * (WM * 16);
  const int wc = (w & 1) * (WN * 16);

  const _Float16* Ag = A + (size_t)m0 * K;
  const _Float16* Bg = Bt + (size_t)n0 * K;

  f32x4 acc[WM][WN];
#pragma unroll
  for (int m = 0; m < WM; ++m)
#pragma unroll
    for (int n = 0; n < WN; ++n) acc[m][n] = f32x4{0.f, 0.f, 0.f, 0.f};

  char* As = smem;
  char* Bs = smem + BM * 128;

  const int kiters = K / 64;
  for (int kt = 0; kt < kiters; ++kt) {
    stage_tile<BM>(Ag, K, As, w, l);
    stage_tile<BN>(Bg, K, Bs, w, l);
    Ag += 64; Bg += 64;
    asm volatile("s_waitcnt vmcnt(0)" ::: "memory");
    __syncthreads();

#pragma unroll
    for (int kk = 0; kk < 2; ++kk) {
      f16x8 afr[WM], bfr[WN];
#pragma unroll
      for (int n = 0; n < WN; ++n) bfr[n] = ldfrag(Bs, wc + n * 16 + lr, kk, lq);
#pragma unroll
      for (int m = 0; m < WM; ++m) afr[m] = ldfrag(As, wr + m * 16 + lr, kk, lq);
#pragma unroll
      for (int m = 0; m < WM; ++m)
#pragma unroll
        for (int n = 0; n < WN; ++n)
          acc[m][n] = __builtin_amdgcn_mfma_f32_16x16x32_f16(afr[m], bfr[n],
                                                             acc[m][n], 0, 0, 0);
    }
    __syncthreads();
  }

  // Epilogue. C/D layout (m89-verified): col = lane&15, row = (lane>>4)*4 + j.
  if (MODE == 0) {
#pragma unroll
    for (int m = 0; m < WM; ++m)
#pragma unroll
      for (int n = 0; n < WN; ++n) {
        const int gcol = n0 + wc + n * 16 + lr;
        const float bv = bias[gcol];
#pragma unroll
        for (int j = 0; j < 4; ++j) {
          const int grow = m0 + wr + m * 16 + lq * 4 + j;
          const float t = fast_tanh(acc[m][n][j] + bv);
          if (gcol < HID)
            Hout[(size_t)grow * HID + gcol] = (_Float16)t;
          else
            kmem[(size_t)grow * DIM + (gcol - HID)] = t;
        }
      }
  } else {
    const float h = tg[step + 1] - tg[step];
#pragma unroll
    for (int m = 0; m < WM; ++m)
#pragma unroll
      for (int n = 0; n < WN; ++n) {
        const int gcol = n0 + wc + n * 16 + lr;
        const float bv = b2[gcol];
#pragma unroll
        for (int j = 0; j < 4; ++j) {
          const int grow = m0 + wr + m * 16 + lq * 4 + j;
          const size_t idx = (size_t)grow * DIM + gcol;
          const float kv = acc[m][n][j] + kmem[idx] + bv;
          if (MODE == 1) {
            const float av = initf ? kv : (accb[idx] + 2.0f * kv);
            accb[idx] = av;
            const float tv = y[idx] + (hmul * h) * kv;
            ts[idx] = (_Float16)tv;
          } else {
            const float v = y[idx] + (h * (1.0f / 6.0f)) * (accb[idx] + kv);
            y[idx] = v;
            out_row[idx] = v;
            ts[idx] = (_Float16)v;
          }
        }
      }
  }
}

// ---------- init + weight prep ----------
__global__ __launch_bounds__(256) void init_k(
    const float* __restrict__ x, float* __restrict__ y,
    float* __restrict__ out0, _Float16* __restrict__ ys) {
  const int i4 = blockIdx.x * 256 + threadIdx.x;
  const int base = i4 * 4;
  f32x4 v = *(const f32x4*)(x + base);
  *(f32x4*)(y + base) = v;
  *(f32x4*)(out0 + base) = v;
  f16x4 hv;
#pragma unroll
  for (int j = 0; j < 4; ++j) hv[j] = (_Float16)v[j];
  *(f16x4*)(ys + base) = hv;
}

__global__ __launch_bounds__(256) void prep_wcat_k(
    const float* __restrict__ W1, const float* __restrict__ Wm,
    _Float16* __restrict__ out) {  // [NCAT][DIM] = concat(W1^T, Wm^T)
  const int idx = blockIdx.x * 256 + threadIdx.x;
  const int nrow = idx / DIM, k = idx % DIM;
  const float v = (nrow < HID) ? W1[(size_t)k * HID + nrow]
                               : Wm[(size_t)k * DIM + (nrow - HID)];
  out[idx] = (_Float16)v;
}
__global__ __launch_bounds__(256) void prep_w2t_k(
    const float* __restrict__ W2, _Float16* __restrict__ out) {  // [DIM][HID]
  const int idx = blockIdx.x * 256 + threadIdx.x;
  const int nrow = idx / HID, k = idx % HID;
  out[idx] = (_Float16)W2[(size_t)k * DIM + nrow];
}
__global__ __launch_bounds__(256) void prep_bias_k(
    const float* __restrict__ b1, const float* __restrict__ bmv,
    float* __restrict__ out) {  // [NCAT]
  const int i = blockIdx.x * 256 + threadIdx.x;
  if (i < NCAT) out[i] = (i < HID) ? b1[i] : bmv[i - HID];
}

extern "C" void kernel_launch(void* const* d_in, const int* in_sizes, int n_in,
                              void* d_out, int out_size, void* d_ws,
                              size_t ws_size, hipStream_t stream) {
  const float* x  = (const float*)d_in[0];
  const float* tg = (const float*)d_in[1];
  const float* W1 = (const float*)d_in[2];
  const float* b1 = (const float*)d_in[3];
  const float* W2 = (const float*)d_in[4];
  const float* b2 = (const float*)d_in[5];
  const float* Wm = (const float*)d_in[6];
  const float* bm = (const float*)d_in[7];
  float* out = (float*)d_out;
  const int T = in_sizes[1];  // 32

  // ---- workspace partition (~36 MB) ----
  float* y        = (float*)d_ws;               // NELEM
  float* accb     = y + NELEM;                  // NELEM
  float* kmem     = accb + NELEM;               // NELEM
  float* bias_cat = kmem + NELEM;               // NCAT
  _Float16* ys    = (_Float16*)(bias_cat + NCAT);  // NELEM (state for k1)
  _Float16* ts    = ys + NELEM;                    // NELEM (stage state)
  _Float16* Hh    = ts + NELEM;                    // BATCH*HID
  _Float16* WcatT = Hh + (size_t)BATCH * HID;      // NCAT*DIM
  _Float16* W2T   = WcatT + (size_t)NCAT * DIM;    // DIM*HID

  // ---- per-launch prep ----
  prep_wcat_k<<<(NCAT * DIM) / 256, 256, 0, stream>>>(W1, Wm, WcatT);
  prep_w2t_k<<<(DIM * HID) / 256, 256, 0, stream>>>(W2, W2T);
  prep_bias_k<<<(NCAT + 255) / 256, 256, 0, stream>>>(b1, bm, bias_cat);
  init_k<<<NELEM / 1024, 256, 0, stream>>>(x, y, out, ys);

  const dim3 g0(NCAT / 128, BATCH / 128);  // 18 x 16 = 288 blocks
  const dim3 g1(DIM / 96, BATCH / 64);     //  8 x 32 = 256 blocks (exact fill)

  auto gemm0 = [&](const _Float16* a) {
    gemm_k<0><<<g0, 256, 0, stream>>>(a, WcatT, bias_cat, Hh, kmem, nullptr,
                                      nullptr, nullptr, nullptr, nullptr,
                                      nullptr, DIM, 0, 0.f, 0);
  };
  auto gemm1_stage = [&](int step, float hmul, int initf) {
    gemm_k<1><<<g1, 256, 0, stream>>>(Hh, W2T, nullptr, nullptr, kmem, b2, y,
                                      accb, ts, nullptr, tg, HID, step, hmul,
                                      initf);
  };
  auto gemm1_final = [&](int step, float* orow) {
    gemm_k<2><<<g1, 256, 0, stream>>>(Hh, W2T, nullptr, nullptr, kmem, b2, y,
                                      accb, ys, orow, tg, HID, step, 0.f, 0);
  };

  for (int i = 0; i < T - 1; ++i) {
    gemm0(ys);  gemm1_stage(i, 0.5f, 1);   // k1
    gemm0(ts);  gemm1_stage(i, 0.5f, 0);   // k2
    gemm0(ts);  gemm1_stage(i, 1.0f, 0);   // k3
    gemm0(ts);  gemm1_final(i, out + (size_t)(i + 1) * NELEM);  // k4
  }
}

// Round 5
// 5005.021 us; speedup vs baseline: 7.2677x; 1.3261x over previous
//
#include <hip/hip_runtime.h>
#include <math.h>

// Problem constants (fixed by the reference).
#define DIM   768
#define HID   1536
#define NCAT  2304            // HID + DIM (W1 | Wm concatenated on output dim)
#define BATCH 2048
#define NELEM (BATCH * DIM)   // 1572864

typedef _Float16 f16x8 __attribute__((ext_vector_type(8)));
typedef _Float16 f16x4 __attribute__((ext_vector_type(4)));
typedef float f32x4 __attribute__((ext_vector_type(4)));

// ---------- numeric helpers ----------
__device__ __forceinline__ float fast_tanh(float x) {
  float e = __expf(2.0f * x);
  return 1.0f - 2.0f / (e + 1.0f);
}

// ---------- async global->LDS staging ----------
#define AS1 __attribute__((address_space(1)))
#define AS3 __attribute__((address_space(3)))
__device__ __forceinline__ void gload_lds16(const void* g, void* l) {
  __builtin_amdgcn_global_load_lds((const AS1 unsigned int*)g,
                                   (AS3 unsigned int*)l, 16, 0, 0);
}

// Stage a ROWSx64 fp16 tile (128 B rows) from row-major [.][K] global into
// LDS. Linear LDS dest (global_load_lds requirement); 16B slot index is
// XOR-swizzled via the GLOBAL source address; reads apply the same swizzle
// (rule #21: linear dest + inverse-swizzled source + swizzled read).
// One wave-issue covers 8 rows (8 slots x 8 rows = 64 lanes).
template <int ROWS>
__device__ __forceinline__ void stage_tile(const _Float16* __restrict__ g,
                                           int K, char* lds, int w, int l) {
  constexpr int NCH = ROWS / 8;   // 1 KiB chunks
  const int sub  = l >> 3;        // row within 8-row chunk (== row & 7)
  const int slot = (l & 7) ^ sub; // inverse-swizzled source slot
#pragma unroll
  for (int i = 0; i < NCH / 4; ++i) {
    const int j = w + i * 4;      // chunk id, wave-uniform
    const int row = j * 8 + sub;
    gload_lds16(g + (size_t)row * K + slot * 8, lds + j * 1024);
  }
}

// Swizzled 16B fragment read. kk = k32 sub-block (0/1), lq = lane>>4.
__device__ __forceinline__ f16x8 ldfrag(const char* base, int row, int kk,
                                        int lq) {
  const int slot = (kk * 4 + lq) ^ (row & 7);
  return *reinterpret_cast<const f16x8*>(base + row * 128 + slot * 16);
}

// ---------- fused MFMA GEMM (fp16 in, fp32 accum), depth-2 pipeline ----------
// Triple-buffered LDS; counted vmcnt keeps 2 tiles of global_load_lds in
// flight across barriers (T3/T4); setprio around the MFMA cluster (T5).
// MODE 0: state GEMM. Tile 64x96 (wave-tile 32x48), grid 768 = 3.0/CU.
//         A = state fp16 [BATCH][DIM], B = WcatT [NCAT][DIM].
//         Epilogue t = tanh(acc+bias): col<HID -> H fp16, else kmem fp32.
// MODE 1: dyn GEMM (A = H, K = HID). Tile 32x96 (wave-tile 16x48),
//         grid 512 = 2.0/CU. Fused RK STAGE epilogue:
//         kv = acc + kmem + b2; accb = init? kv : accb+2kv;
//         tv = y + hmul*h*kv -> ts fp16.
// MODE 2: as MODE 1 but RK FINAL epilogue:
//         kv = acc + kmem + b2; y += h/6*(accb+kv); out_row = y; ts = fp16(y).
template <int MODE, int BM, int BN, int KITERS>
__global__ __launch_bounds__(256, 2) void gemm_k(
    const _Float16* __restrict__ A, const _Float16* __restrict__ Bt,
    const float* __restrict__ bias, _Float16* __restrict__ Hout,
    float* __restrict__ kmem, const float* __restrict__ b2,
    float* __restrict__ y, float* __restrict__ accb,
    _Float16* __restrict__ ts, float* __restrict__ out_row,
    const float* __restrict__ tg, int step, float hmul, int initf) {
  constexpr int K = KITERS * 64;
  constexpr int WM = BM / 32;      // m-frags per wave (2x2 wave grid)
  constexpr int WN = BN / 32;      // n-frags per wave
  constexpr int BUF = (BM + BN) * 128;       // one K64 double-tile
  constexpr int SISS = BM / 32 + BN / 32;    // stage issues per wave per tile
  __shared__ __align__(16) char smem[3 * BUF];

  const int tid = threadIdx.x;
  const int w = tid >> 6, l = tid & 63;
  const int lr = l & 15, lq = l >> 4;
  const int m0 = blockIdx.y * BM;
  const int n0 = blockIdx.x * BN;
  const int wr = (w >> 1) * (WM * 16);
  const int wc = (w & 1) * (WN * 16);

  const _Float16* Ag = A + (size_t)m0 * K;
  const _Float16* Bg = Bt + (size_t)n0 * K;

  f32x4 acc[WM][WN];
#pragma unroll
  for (int m = 0; m < WM; ++m)
#pragma unroll
    for (int n = 0; n < WN; ++n) acc[m][n] = f32x4{0.f, 0.f, 0.f, 0.f};

  auto STAGE = [&](int t) {
    char* base = smem + (t % 3) * BUF;
    stage_tile<BM>(Ag + t * 64, K, base, w, l);
    stage_tile<BN>(Bg + t * 64, K, base + BM * 128, w, l);
  };

  STAGE(0);
  if (KITERS > 1) STAGE(1);

  for (int kt = 0; kt < KITERS; ++kt) {
    // Wait for tile kt's own-wave loads only; tile kt+1 stays in flight.
    if (kt + 1 < KITERS)
      asm volatile("s_waitcnt vmcnt(%0)" ::"n"(SISS) : "memory");
    else
      asm volatile("s_waitcnt vmcnt(0)" ::: "memory");
    __syncthreads();
    if (kt + 2 < KITERS) STAGE(kt + 2);

    const char* As = smem + (kt % 3) * BUF;
    const char* Bs = As + BM * 128;
#pragma unroll
    for (int kk = 0; kk < 2; ++kk) {
      f16x8 afr[WM], bfr[WN];
#pragma unroll
      for (int n = 0; n < WN; ++n) bfr[n] = ldfrag(Bs, wc + n * 16 + lr, kk, lq);
#pragma unroll
      for (int m = 0; m < WM; ++m) afr[m] = ldfrag(As, wr + m * 16 + lr, kk, lq);
      __builtin_amdgcn_s_setprio(1);
#pragma unroll
      for (int m = 0; m < WM; ++m)
#pragma unroll
        for (int n = 0; n < WN; ++n)
          acc[m][n] = __builtin_amdgcn_mfma_f32_16x16x32_f16(afr[m], bfr[n],
                                                             acc[m][n], 0, 0, 0);
      __builtin_amdgcn_s_setprio(0);
    }
    __syncthreads();
  }

  // Epilogue. C/D layout (m89-verified): col = lane&15, row = (lane>>4)*4 + j.
  if (MODE == 0) {
#pragma unroll
    for (int m = 0; m < WM; ++m)
#pragma unroll
      for (int n = 0; n < WN; ++n) {
        const int gcol = n0 + wc + n * 16 + lr;
        const float bv = bias[gcol];
#pragma unroll
        for (int j = 0; j < 4; ++j) {
          const int grow = m0 + wr + m * 16 + lq * 4 + j;
          const float t = fast_tanh(acc[m][n][j] + bv);
          if (gcol < HID)
            Hout[(size_t)grow * HID + gcol] = (_Float16)t;
          else
            kmem[(size_t)grow * DIM + (gcol - HID)] = t;
        }
      }
  } else {
    const float h = tg[step + 1] - tg[step];
#pragma unroll
    for (int m = 0; m < WM; ++m)
#pragma unroll
      for (int n = 0; n < WN; ++n) {
        const int gcol = n0 + wc + n * 16 + lr;
        const float bv = b2[gcol];
#pragma unroll
        for (int j = 0; j < 4; ++j) {
          const int grow = m0 + wr + m * 16 + lq * 4 + j;
          const size_t idx = (size_t)grow * DIM + gcol;
          const float kv = acc[m][n][j] + kmem[idx] + bv;
          if (MODE == 1) {
            const float av = initf ? kv : (accb[idx] + 2.0f * kv);
            accb[idx] = av;
            const float tv = y[idx] + (hmul * h) * kv;
            ts[idx] = (_Float16)tv;
          } else {
            const float v = y[idx] + (h * (1.0f / 6.0f)) * (accb[idx] + kv);
            y[idx] = v;
            out_row[idx] = v;
            ts[idx] = (_Float16)v;
          }
        }
      }
  }
}

// ---------- init + weight prep ----------
__global__ __launch_bounds__(256) void init_k(
    const float* __restrict__ x, float* __restrict__ y,
    float* __restrict__ out0, _Float16* __restrict__ ys) {
  const int i4 = blockIdx.x * 256 + threadIdx.x;
  const int base = i4 * 4;
  f32x4 v = *(const f32x4*)(x + base);
  *(f32x4*)(y + base) = v;
  *(f32x4*)(out0 + base) = v;
  f16x4 hv;
#pragma unroll
  for (int j = 0; j < 4; ++j) hv[j] = (_Float16)v[j];
  *(f16x4*)(ys + base) = hv;
}

__global__ __launch_bounds__(256) void prep_wcat_k(
    const float* __restrict__ W1, const float* __restrict__ Wm,
    _Float16* __restrict__ out) {  // [NCAT][DIM] = concat(W1^T, Wm^T)
  const int idx = blockIdx.x * 256 + threadIdx.x;
  const int nrow = idx / DIM, k = idx % DIM;
  const float v = (nrow < HID) ? W1[(size_t)k * HID + nrow]
                               : Wm[(size_t)k * DIM + (nrow - HID)];
  out[idx] = (_Float16)v;
}
__global__ __launch_bounds__(256) void prep_w2t_k(
    const float* __restrict__ W2, _Float16* __restrict__ out) {  // [DIM][HID]
  const int idx = blockIdx.x * 256 + threadIdx.x;
  const int nrow = idx / HID, k = idx % HID;
  out[idx] = (_Float16)W2[(size_t)k * DIM + nrow];
}
__global__ __launch_bounds__(256) void prep_bias_k(
    const float* __restrict__ b1, const float* __restrict__ bmv,
    float* __restrict__ out) {  // [NCAT]
  const int i = blockIdx.x * 256 + threadIdx.x;
  if (i < NCAT) out[i] = (i < HID) ? b1[i] : bmv[i - HID];
}

extern "C" void kernel_launch(void* const* d_in, const int* in_sizes, int n_in,
                              void* d_out, int out_size, void* d_ws,
                              size_t ws_size, hipStream_t stream) {
  const float* x  = (const float*)d_in[0];
  const float* tg = (const float*)d_in[1];
  const float* W1 = (const float*)d_in[2];
  const float* b1 = (const float*)d_in[3];
  const float* W2 = (const float*)d_in[4];
  const float* b2 = (const float*)d_in[5];
  const float* Wm = (const float*)d_in[6];
  const float* bm = (const float*)d_in[7];
  float* out = (float*)d_out;
  const int T = in_sizes[1];  // 32

  // ---- workspace partition (~36 MB) ----
  float* y        = (float*)d_ws;               // NELEM
  float* accb     = y + NELEM;                  // NELEM
  float* kmem     = accb + NELEM;               // NELEM
  float* bias_cat = kmem + NELEM;               // NCAT
  _Float16* ys    = (_Float16*)(bias_cat + NCAT);  // NELEM (state for k1)
  _Float16* ts    = ys + NELEM;                    // NELEM (stage state)
  _Float16* Hh    = ts + NELEM;                    // BATCH*HID
  _Float16* WcatT = Hh + (size_t)BATCH * HID;      // NCAT*DIM
  _Float16* W2T   = WcatT + (size_t)NCAT * DIM;    // DIM*HID

  // ---- per-launch prep ----
  prep_wcat_k<<<(NCAT * DIM) / 256, 256, 0, stream>>>(W1, Wm, WcatT);
  prep_w2t_k<<<(DIM * HID) / 256, 256, 0, stream>>>(W2, W2T);
  prep_bias_k<<<(NCAT + 255) / 256, 256, 0, stream>>>(b1, bm, bias_cat);
  init_k<<<NELEM / 1024, 256, 0, stream>>>(x, y, out, ys);

  const dim3 g0(NCAT / 96, BATCH / 64);  // 24 x 32 = 768 blocks = 3.0/CU
  const dim3 g1(DIM / 96, BATCH / 32);   //  8 x 64 = 512 blocks = 2.0/CU

  auto gemm0 = [&](const _Float16* a) {
    gemm_k<0, 64, 96, 12><<<g0, 256, 0, stream>>>(
        a, WcatT, bias_cat, Hh, kmem, nullptr, nullptr, nullptr, nullptr,
        nullptr, nullptr, 0, 0.f, 0);
  };
  auto gemm1_stage = [&](int step, float hmul, int initf) {
    gemm_k<1, 32, 96, 24><<<g1, 256, 0, stream>>>(
        Hh, W2T, nullptr, nullptr, kmem, b2, y, accb, ts, nullptr, tg, step,
        hmul, initf);
  };
  auto gemm1_final = [&](int step, float* orow) {
    gemm_k<2, 32, 96, 24><<<g1, 256, 0, stream>>>(
        Hh, W2T, nullptr, nullptr, kmem, b2, y, accb, ys, orow, tg, step, 0.f,
        0);
  };

  for (int i = 0; i < T - 1; ++i) {
    gemm0(ys);  gemm1_stage(i, 0.5f, 1);   // k1
    gemm0(ts);  gemm1_stage(i, 0.5f, 0);   // k2
    gemm0(ts);  gemm1_stage(i, 1.0f, 0);   // k3
    gemm0(ts);  gemm1_final(i, out + (size_t)(i + 1) * NELEM);  // k4
  }
}

// Round 6
// 4339.138 us; speedup vs baseline: 8.3830x; 1.1535x over previous
//
#include <hip/hip_runtime.h>
#include <math.h>

// Problem constants (fixed by the reference).
#define DIM   768
#define HID   1536
#define NCAT  2304            // HID + DIM (W1 | Wm concatenated on output dim)
#define BATCH 2048
#define NELEM (BATCH * DIM)   // 1572864

typedef _Float16 f16x8 __attribute__((ext_vector_type(8)));
typedef _Float16 f16x4 __attribute__((ext_vector_type(4)));
typedef float f32x4 __attribute__((ext_vector_type(4)));

// ---------- numeric helpers ----------
__device__ __forceinline__ float fast_tanh(float x) {
  float e = __expf(2.0f * x);
  return 1.0f - 2.0f / (e + 1.0f);
}

// ---------- async global->LDS staging ----------
#define AS1 __attribute__((address_space(1)))
#define AS3 __attribute__((address_space(3)))
__device__ __forceinline__ void gload_lds16(const void* g, void* l) {
  __builtin_amdgcn_global_load_lds((const AS1 unsigned int*)g,
                                   (AS3 unsigned int*)l, 16, 0, 0);
}

// Stage a ROWSx64 fp16 tile (128 B rows) from row-major [.][K] global into
// LDS. Linear LDS dest (global_load_lds requirement); 16B slot index is
// XOR-swizzled via the GLOBAL source address; reads apply the same swizzle
// (rule #21: linear dest + inverse-swizzled source + swizzled read).
// One wave-issue covers 8 rows (8 slots x 8 rows = 64 lanes).
template <int ROWS>
__device__ __forceinline__ void stage_tile(const _Float16* __restrict__ g,
                                           int K, char* lds, int w, int l) {
  constexpr int NCH = ROWS / 8;   // 1 KiB chunks
  const int sub  = l >> 3;        // row within 8-row chunk (== row & 7)
  const int slot = (l & 7) ^ sub; // inverse-swizzled source slot
#pragma unroll
  for (int i = 0; i < NCH / 4; ++i) {
    const int j = w + i * 4;      // chunk id, wave-uniform
    const int row = j * 8 + sub;
    gload_lds16(g + (size_t)row * K + slot * 8, lds + j * 1024);
  }
}

// Swizzled 16B fragment read. kk = k32 sub-block (0/1), lq = lane>>4.
__device__ __forceinline__ f16x8 ldfrag(const char* base, int row, int kk,
                                        int lq) {
  const int slot = (kk * 4 + lq) ^ (row & 7);
  return *reinterpret_cast<const f16x8*>(base + row * 128 + slot * 16);
}

// ---------- fused MFMA GEMM (fp16 in, fp32 accum), depth-2 pipeline ----------
// Triple-buffered LDS. ONE raw s_barrier per K-step, placed after a COUNTED
// s_waitcnt vmcnt(SISS) — tile kt+1's global_load_lds stays in flight across
// the barrier (T3/T4). __syncthreads() is deliberately NOT used: hipcc pairs
// it with a full vmcnt(0) drain, which defeats the pipeline (m97 stall).
// Safety of the single barrier: a wave reaches barrier(kt) only after its
// compute(kt-1) MFMAs issued, which required those ds_reads to have RETURNED
// (lgkmcnt-enforced) — so STAGE(kt+2) (which overwrites buf[(kt-1)%3]) can
// never clobber LDS with pending readers.
// MODE 0: state GEMM. Tile 64x96 (wave-tile 32x48), grid 768 = 3.0/CU... (2
//         resident by LDS). A = state fp16, B = WcatT. Epilogue
//         t = tanh(acc+bias): col<HID -> H fp16, else kmem fp32.
// MODE 1: dyn GEMM (A = H, K = HID). Tile 32x96, grid 512. Fused RK STAGE:
//         kv = acc + kmem + b2; accb = init? kv : accb+2kv;
//         tv = y + hmul*h*kv -> ts fp16.
// MODE 2: as MODE 1 but RK FINAL:
//         kv = acc + kmem + b2; y += h/6*(accb+kv); out_row = y; ts = fp16(y).
template <int MODE, int BM, int BN, int KITERS>
__global__ __launch_bounds__(256, 2) void gemm_k(
    const _Float16* __restrict__ A, const _Float16* __restrict__ Bt,
    const float* __restrict__ bias, _Float16* __restrict__ Hout,
    float* __restrict__ kmem, const float* __restrict__ b2,
    float* __restrict__ y, float* __restrict__ accb,
    _Float16* __restrict__ ts, float* __restrict__ out_row,
    const float* __restrict__ tg, int step, float hmul, int initf) {
  constexpr int K = KITERS * 64;
  constexpr int WM = BM / 32;      // m-frags per wave (2x2 wave grid)
  constexpr int WN = BN / 32;      // n-frags per wave
  constexpr int BUF = (BM + BN) * 128;       // one K64 double-tile
  constexpr int SISS = BM / 32 + BN / 32;    // stage issues per wave per tile
  __shared__ __align__(16) char smem[3 * BUF];

  const int tid = threadIdx.x;
  const int w = tid >> 6, l = tid & 63;
  const int lr = l & 15, lq = l >> 4;
  const int m0 = blockIdx.y * BM;
  const int n0 = blockIdx.x * BN;
  const int wr = (w >> 1) * (WM * 16);
  const int wc = (w & 1) * (WN * 16);

  const _Float16* Ag = A + (size_t)m0 * K;
  const _Float16* Bg = Bt + (size_t)n0 * K;

  f32x4 acc[WM][WN];
#pragma unroll
  for (int m = 0; m < WM; ++m)
#pragma unroll
    for (int n = 0; n < WN; ++n) acc[m][n] = f32x4{0.f, 0.f, 0.f, 0.f};

  auto STAGE = [&](int t) {
    char* base = smem + (t % 3) * BUF;
    stage_tile<BM>(Ag + t * 64, K, base, w, l);
    stage_tile<BN>(Bg + t * 64, K, base + BM * 128, w, l);
  };

  STAGE(0);
  if (KITERS > 1) STAGE(1);

  for (int kt = 0; kt < KITERS; ++kt) {
    // Wait for tile kt's own-wave loads only; tile kt+1 stays in flight
    // ACROSS the raw barrier (no compiler vmcnt(0) drain).
    if (kt + 1 < KITERS)
      asm volatile("s_waitcnt vmcnt(%0)" ::"n"(SISS) : "memory");
    else
      asm volatile("s_waitcnt vmcnt(0)" ::: "memory");
    __builtin_amdgcn_s_barrier();
    __builtin_amdgcn_sched_barrier(0);
    if (kt + 2 < KITERS) STAGE(kt + 2);

    const char* As = smem + (kt % 3) * BUF;
    const char* Bs = As + BM * 128;
#pragma unroll
    for (int kk = 0; kk < 2; ++kk) {
      f16x8 afr[WM], bfr[WN];
#pragma unroll
      for (int n = 0; n < WN; ++n) bfr[n] = ldfrag(Bs, wc + n * 16 + lr, kk, lq);
#pragma unroll
      for (int m = 0; m < WM; ++m) afr[m] = ldfrag(As, wr + m * 16 + lr, kk, lq);
      __builtin_amdgcn_s_setprio(1);
#pragma unroll
      for (int m = 0; m < WM; ++m)
#pragma unroll
        for (int n = 0; n < WN; ++n)
          acc[m][n] = __builtin_amdgcn_mfma_f32_16x16x32_f16(afr[m], bfr[n],
                                                             acc[m][n], 0, 0, 0);
      __builtin_amdgcn_s_setprio(0);
    }
  }

  // Epilogue. C/D layout (m89-verified): col = lane&15, row = (lane>>4)*4 + j.
  if (MODE == 0) {
#pragma unroll
    for (int m = 0; m < WM; ++m)
#pragma unroll
      for (int n = 0; n < WN; ++n) {
        const int gcol = n0 + wc + n * 16 + lr;
        const float bv = bias[gcol];
#pragma unroll
        for (int j = 0; j < 4; ++j) {
          const int grow = m0 + wr + m * 16 + lq * 4 + j;
          const float t = fast_tanh(acc[m][n][j] + bv);
          if (gcol < HID)
            Hout[(size_t)grow * HID + gcol] = (_Float16)t;
          else
            kmem[(size_t)grow * DIM + (gcol - HID)] = t;
        }
      }
  } else {
    const float h = tg[step + 1] - tg[step];
#pragma unroll
    for (int m = 0; m < WM; ++m)
#pragma unroll
      for (int n = 0; n < WN; ++n) {
        const int gcol = n0 + wc + n * 16 + lr;
        const float bv = b2[gcol];
#pragma unroll
        for (int j = 0; j < 4; ++j) {
          const int grow = m0 + wr + m * 16 + lq * 4 + j;
          const size_t idx = (size_t)grow * DIM + gcol;
          const float kv = acc[m][n][j] + kmem[idx] + bv;
          if (MODE == 1) {
            const float av = initf ? kv : (accb[idx] + 2.0f * kv);
            accb[idx] = av;
            const float tv = y[idx] + (hmul * h) * kv;
            ts[idx] = (_Float16)tv;
          } else {
            const float v = y[idx] + (h * (1.0f / 6.0f)) * (accb[idx] + kv);
            y[idx] = v;
            out_row[idx] = v;
            ts[idx] = (_Float16)v;
          }
        }
      }
  }
}

// ---------- init + weight prep ----------
__global__ __launch_bounds__(256) void init_k(
    const float* __restrict__ x, float* __restrict__ y,
    float* __restrict__ out0, _Float16* __restrict__ ys) {
  const int i4 = blockIdx.x * 256 + threadIdx.x;
  const int base = i4 * 4;
  f32x4 v = *(const f32x4*)(x + base);
  *(f32x4*)(y + base) = v;
  *(f32x4*)(out0 + base) = v;
  f16x4 hv;
#pragma unroll
  for (int j = 0; j < 4; ++j) hv[j] = (_Float16)v[j];
  *(f16x4*)(ys + base) = hv;
}

__global__ __launch_bounds__(256) void prep_wcat_k(
    const float* __restrict__ W1, const float* __restrict__ Wm,
    _Float16* __restrict__ out) {  // [NCAT][DIM] = concat(W1^T, Wm^T)
  const int idx = blockIdx.x * 256 + threadIdx.x;
  const int nrow = idx / DIM, k = idx % DIM;
  const float v = (nrow < HID) ? W1[(size_t)k * HID + nrow]
                               : Wm[(size_t)k * DIM + (nrow - HID)];
  out[idx] = (_Float16)v;
}
__global__ __launch_bounds__(256) void prep_w2t_k(
    const float* __restrict__ W2, _Float16* __restrict__ out) {  // [DIM][HID]
  const int idx = blockIdx.x * 256 + threadIdx.x;
  const int nrow = idx / HID, k = idx % HID;
  out[idx] = (_Float16)W2[(size_t)k * DIM + nrow];
}
__global__ __launch_bounds__(256) void prep_bias_k(
    const float* __restrict__ b1, const float* __restrict__ bmv,
    float* __restrict__ out) {  // [NCAT]
  const int i = blockIdx.x * 256 + threadIdx.x;
  if (i < NCAT) out[i] = (i < HID) ? b1[i] : bmv[i - HID];
}

extern "C" void kernel_launch(void* const* d_in, const int* in_sizes, int n_in,
                              void* d_out, int out_size, void* d_ws,
                              size_t ws_size, hipStream_t stream) {
  const float* x  = (const float*)d_in[0];
  const float* tg = (const float*)d_in[1];
  const float* W1 = (const float*)d_in[2];
  const float* b1 = (const float*)d_in[3];
  const float* W2 = (const float*)d_in[4];
  const float* b2 = (const float*)d_in[5];
  const float* Wm = (const float*)d_in[6];
  const float* bm = (const float*)d_in[7];
  float* out = (float*)d_out;
  const int T = in_sizes[1];  // 32

  // ---- workspace partition (~36 MB) ----
  float* y        = (float*)d_ws;               // NELEM
  float* accb     = y + NELEM;                  // NELEM
  float* kmem     = accb + NELEM;               // NELEM
  float* bias_cat = kmem + NELEM;               // NCAT
  _Float16* ys    = (_Float16*)(bias_cat + NCAT);  // NELEM (state for k1)
  _Float16* ts    = ys + NELEM;                    // NELEM (stage state)
  _Float16* Hh    = ts + NELEM;                    // BATCH*HID
  _Float16* WcatT = Hh + (size_t)BATCH * HID;      // NCAT*DIM
  _Float16* W2T   = WcatT + (size_t)NCAT * DIM;    // DIM*HID

  // ---- per-launch prep ----
  prep_wcat_k<<<(NCAT * DIM) / 256, 256, 0, stream>>>(W1, Wm, WcatT);
  prep_w2t_k<<<(DIM * HID) / 256, 256, 0, stream>>>(W2, W2T);
  prep_bias_k<<<(NCAT + 255) / 256, 256, 0, stream>>>(b1, bm, bias_cat);
  init_k<<<NELEM / 1024, 256, 0, stream>>>(x, y, out, ys);

  const dim3 g0(NCAT / 96, BATCH / 64);  // 24 x 32 = 768 blocks
  const dim3 g1(DIM / 96, BATCH / 32);   //  8 x 64 = 512 blocks

  auto gemm0 = [&](const _Float16* a) {
    gemm_k<0, 64, 96, 12><<<g0, 256, 0, stream>>>(
        a, WcatT, bias_cat, Hh, kmem, nullptr, nullptr, nullptr, nullptr,
        nullptr, nullptr, 0, 0.f, 0);
  };
  auto gemm1_stage = [&](int step, float hmul, int initf) {
    gemm_k<1, 32, 96, 24><<<g1, 256, 0, stream>>>(
        Hh, W2T, nullptr, nullptr, kmem, b2, y, accb, ts, nullptr, tg, step,
        hmul, initf);
  };
  auto gemm1_final = [&](int step, float* orow) {
    gemm_k<2, 32, 96, 24><<<g1, 256, 0, stream>>>(
        Hh, W2T, nullptr, nullptr, kmem, b2, y, accb, ys, orow, tg, step, 0.f,
        0);
  };

  for (int i = 0; i < T - 1; ++i) {
    gemm0(ys);  gemm1_stage(i, 0.5f, 1);   // k1
    gemm0(ts);  gemm1_stage(i, 0.5f, 0);   // k2
    gemm0(ts);  gemm1_stage(i, 1.0f, 0);   // k3
    gemm0(ts);  gemm1_final(i, out + (size_t)(i + 1) * NELEM);  // k4
  }
}

// Round 7
// 4177.806 us; speedup vs baseline: 8.7067x; 1.0386x over previous
//
#include <hip/hip_runtime.h>
#include <math.h>

// Problem constants (fixed by the reference).
#define DIM   768
#define HID   1536
#define NCAT  2304            // HID + DIM (W1 | Wm concatenated on output dim)
#define BATCH 2048
#define NELEM (BATCH * DIM)   // 1572864

typedef _Float16 f16x8 __attribute__((ext_vector_type(8)));
typedef _Float16 f16x4 __attribute__((ext_vector_type(4)));
typedef float f32x4 __attribute__((ext_vector_type(4)));

// ---------- numeric helpers ----------
__device__ __forceinline__ float fast_tanh(float x) {
  float e = __expf(2.0f * x);
  return 1.0f - 2.0f / (e + 1.0f);
}

// ---------- async global->LDS staging ----------
#define AS1 __attribute__((address_space(1)))
#define AS3 __attribute__((address_space(3)))
__device__ __forceinline__ void gload_lds16(const void* g, void* l) {
  __builtin_amdgcn_global_load_lds((const AS1 unsigned int*)g,
                                   (AS3 unsigned int*)l, 16, 0, 0);
}

// Stage a ROWSx64 fp16 tile (128 B rows) from row-major [.][K] global into
// LDS. Linear LDS dest (global_load_lds requirement); 16B slot index is
// XOR-swizzled via the GLOBAL source address; reads apply the same swizzle
// (rule #21: linear dest + inverse-swizzled source + swizzled read).
// One wave-issue covers 8 rows (8 slots x 8 rows = 64 lanes).
template <int ROWS>
__device__ __forceinline__ void stage_tile(const _Float16* __restrict__ g,
                                           int K, char* lds, int w, int l) {
  constexpr int NCH = ROWS / 8;   // 1 KiB chunks
  const int sub  = l >> 3;        // row within 8-row chunk (== row & 7)
  const int slot = (l & 7) ^ sub; // inverse-swizzled source slot
#pragma unroll
  for (int i = 0; i < NCH / 4; ++i) {
    const int j = w + i * 4;      // chunk id, wave-uniform
    const int row = j * 8 + sub;
    gload_lds16(g + (size_t)row * K + slot * 8, lds + j * 1024);
  }
}

// Swizzled 16B fragment read. kk = k32 sub-block (0/1), lq = lane>>4.
__device__ __forceinline__ f16x8 ldfrag(const char* base, int row, int kk,
                                        int lq) {
  const int slot = (kk * 4 + lq) ^ (row & 7);
  return *reinterpret_cast<const f16x8*>(base + row * 128 + slot * 16);
}

// ---------- fused MFMA GEMM (fp16 in, fp32 accum), pipelined ----------
// MODE 0 uses DOUBLE-buffered LDS (40 KB -> 4 blocks/CU capacity; grid 768
//   = 3/CU ALL-RESIDENT and balanced — the triple-buffer 60 KB variant capped
//   residency at 2/CU and serialized 768 blocks into 1.5 rounds) with a
//   depth-1 prefetch and TWO raw s_barriers per K-step.
// MODE 1/2 keep TRIPLE-buffered depth-2 with ONE barrier per K-step
//   (30 KB, grid 512 = 2/CU resident-balanced).
// In both schemes the counted s_waitcnt vmcnt(SISS) sits BEFORE the barrier,
// so collectively all waves' staging of tile kt is complete when any wave
// passes; vmcnt never drains to 0 mid-loop (in-flight prefetch crosses the
// barrier). __syncthreads() deliberately unused (hipcc pairs it with a full
// vmcnt(0) drain — the m97 stall).
// WAR safety (dbuf): STAGE(kt+1) writes buf[(kt+1)&1], whose last readers
// (compute(kt-1)) completed their ds_reads before their MFMAs issued
// (lgkm-enforced) and are fenced by the trailing barrier of iter kt-1.
// MODE 0: state GEMM. Tile 64x96 (wave-tile 32x48). A = state fp16,
//         B = WcatT. Epilogue t = tanh(acc+bias): col<HID -> H fp16,
//         else kmem fp32.
// MODE 1: dyn GEMM (A = H, K = HID). Tile 32x96, grid 512. Fused RK STAGE:
//         kv = acc + kmem + b2; accb = init? kv : accb+2kv;
//         tv = y + hmul*h*kv -> ts fp16.
// MODE 2: as MODE 1 but RK FINAL:
//         kv = acc + kmem + b2; y += h/6*(accb+kv); out_row = y; ts = fp16(y).
template <int MODE, int BM, int BN, int KITERS>
__global__ __launch_bounds__(256, (MODE == 0) ? 3 : 2) void gemm_k(
    const _Float16* __restrict__ A, const _Float16* __restrict__ Bt,
    const float* __restrict__ bias, _Float16* __restrict__ Hout,
    float* __restrict__ kmem, const float* __restrict__ b2,
    float* __restrict__ y, float* __restrict__ accb,
    _Float16* __restrict__ ts, float* __restrict__ out_row,
    const float* __restrict__ tg, int step, float hmul, int initf) {
  constexpr int K = KITERS * 64;
  constexpr int WM = BM / 32;      // m-frags per wave (2x2 wave grid)
  constexpr int WN = BN / 32;      // n-frags per wave
  constexpr int BUF = (BM + BN) * 128;       // one K64 double-tile
  constexpr int NBUF = (MODE == 0) ? 2 : 3;  // buffers in rotation
  constexpr int SISS = BM / 32 + BN / 32;    // stage issues per wave per tile
  __shared__ __align__(16) char smem[NBUF * BUF];

  const int tid = threadIdx.x;
  const int w = tid >> 6, l = tid & 63;
  const int lr = l & 15, lq = l >> 4;
  const int m0 = blockIdx.y * BM;
  const int n0 = blockIdx.x * BN;
  const int wr = (w >> 1) * (WM * 16);
  const int wc = (w & 1) * (WN * 16);

  const _Float16* Ag = A + (size_t)m0 * K;
  const _Float16* Bg = Bt + (size_t)n0 * K;

  f32x4 acc[WM][WN];
#pragma unroll
  for (int m = 0; m < WM; ++m)
#pragma unroll
    for (int n = 0; n < WN; ++n) acc[m][n] = f32x4{0.f, 0.f, 0.f, 0.f};

  auto STAGE = [&](int t) {
    char* base = smem + (t % NBUF) * BUF;
    stage_tile<BM>(Ag + t * 64, K, base, w, l);
    stage_tile<BN>(Bg + t * 64, K, base + BM * 128, w, l);
  };

  STAGE(0);
  if (NBUF == 3 && KITERS > 1) STAGE(1);

  for (int kt = 0; kt < KITERS; ++kt) {
    if (NBUF == 2 && kt + 1 < KITERS) STAGE(kt + 1);
    // Wait for tile kt's own-wave loads only; newer tiles stay in flight
    // ACROSS the raw barrier (no compiler vmcnt(0) drain).
    if (kt + 1 < KITERS)
      asm volatile("s_waitcnt vmcnt(%0)" ::"n"(SISS) : "memory");
    else
      asm volatile("s_waitcnt vmcnt(0)" ::: "memory");
    __builtin_amdgcn_s_barrier();
    __builtin_amdgcn_sched_barrier(0);
    if (NBUF == 3 && kt + 2 < KITERS) STAGE(kt + 2);

    const char* As = smem + (kt % NBUF) * BUF;
    const char* Bs = As + BM * 128;
#pragma unroll
    for (int kk = 0; kk < 2; ++kk) {
      f16x8 afr[WM], bfr[WN];
#pragma unroll
      for (int n = 0; n < WN; ++n) bfr[n] = ldfrag(Bs, wc + n * 16 + lr, kk, lq);
#pragma unroll
      for (int m = 0; m < WM; ++m) afr[m] = ldfrag(As, wr + m * 16 + lr, kk, lq);
      __builtin_amdgcn_s_setprio(1);
#pragma unroll
      for (int m = 0; m < WM; ++m)
#pragma unroll
        for (int n = 0; n < WN; ++n)
          acc[m][n] = __builtin_amdgcn_mfma_f32_16x16x32_f16(afr[m], bfr[n],
                                                             acc[m][n], 0, 0, 0);
      __builtin_amdgcn_s_setprio(0);
    }
    if (NBUF == 2) __builtin_amdgcn_s_barrier();  // fence buf rewrite next iter
  }

  // Epilogue. C/D layout (m89-verified): col = lane&15, row = (lane>>4)*4 + j.
  if (MODE == 0) {
#pragma unroll
    for (int m = 0; m < WM; ++m)
#pragma unroll
      for (int n = 0; n < WN; ++n) {
        const int gcol = n0 + wc + n * 16 + lr;
        const float bv = bias[gcol];
#pragma unroll
        for (int j = 0; j < 4; ++j) {
          const int grow = m0 + wr + m * 16 + lq * 4 + j;
          const float t = fast_tanh(acc[m][n][j] + bv);
          if (gcol < HID)
            Hout[(size_t)grow * HID + gcol] = (_Float16)t;
          else
            kmem[(size_t)grow * DIM + (gcol - HID)] = t;
        }
      }
  } else {
    const float h = tg[step + 1] - tg[step];
#pragma unroll
    for (int m = 0; m < WM; ++m)
#pragma unroll
      for (int n = 0; n < WN; ++n) {
        const int gcol = n0 + wc + n * 16 + lr;
        const float bv = b2[gcol];
#pragma unroll
        for (int j = 0; j < 4; ++j) {
          const int grow = m0 + wr + m * 16 + lq * 4 + j;
          const size_t idx = (size_t)grow * DIM + gcol;
          const float kv = acc[m][n][j] + kmem[idx] + bv;
          if (MODE == 1) {
            const float av = initf ? kv : (accb[idx] + 2.0f * kv);
            accb[idx] = av;
            const float tv = y[idx] + (hmul * h) * kv;
            ts[idx] = (_Float16)tv;
          } else {
            const float v = y[idx] + (h * (1.0f / 6.0f)) * (accb[idx] + kv);
            y[idx] = v;
            out_row[idx] = v;
            ts[idx] = (_Float16)v;
          }
        }
      }
  }
}

// ---------- init + weight prep ----------
__global__ __launch_bounds__(256) void init_k(
    const float* __restrict__ x, float* __restrict__ y,
    float* __restrict__ out0, _Float16* __restrict__ ys) {
  const int i4 = blockIdx.x * 256 + threadIdx.x;
  const int base = i4 * 4;
  f32x4 v = *(const f32x4*)(x + base);
  *(f32x4*)(y + base) = v;
  *(f32x4*)(out0 + base) = v;
  f16x4 hv;
#pragma unroll
  for (int j = 0; j < 4; ++j) hv[j] = (_Float16)v[j];
  *(f16x4*)(ys + base) = hv;
}

__global__ __launch_bounds__(256) void prep_wcat_k(
    const float* __restrict__ W1, const float* __restrict__ Wm,
    _Float16* __restrict__ out) {  // [NCAT][DIM] = concat(W1^T, Wm^T)
  const int idx = blockIdx.x * 256 + threadIdx.x;
  const int nrow = idx / DIM, k = idx % DIM;
  const float v = (nrow < HID) ? W1[(size_t)k * HID + nrow]
                               : Wm[(size_t)k * DIM + (nrow - HID)];
  out[idx] = (_Float16)v;
}
__global__ __launch_bounds__(256) void prep_w2t_k(
    const float* __restrict__ W2, _Float16* __restrict__ out) {  // [DIM][HID]
  const int idx = blockIdx.x * 256 + threadIdx.x;
  const int nrow = idx / HID, k = idx % HID;
  out[idx] = (_Float16)W2[(size_t)k * DIM + nrow];
}
__global__ __launch_bounds__(256) void prep_bias_k(
    const float* __restrict__ b1, const float* __restrict__ bmv,
    float* __restrict__ out) {  // [NCAT]
  const int i = blockIdx.x * 256 + threadIdx.x;
  if (i < NCAT) out[i] = (i < HID) ? b1[i] : bmv[i - HID];
}

extern "C" void kernel_launch(void* const* d_in, const int* in_sizes, int n_in,
                              void* d_out, int out_size, void* d_ws,
                              size_t ws_size, hipStream_t stream) {
  const float* x  = (const float*)d_in[0];
  const float* tg = (const float*)d_in[1];
  const float* W1 = (const float*)d_in[2];
  const float* b1 = (const float*)d_in[3];
  const float* W2 = (const float*)d_in[4];
  const float* b2 = (const float*)d_in[5];
  const float* Wm = (const float*)d_in[6];
  const float* bm = (const float*)d_in[7];
  float* out = (float*)d_out;
  const int T = in_sizes[1];  // 32

  // ---- workspace partition (~36 MB) ----
  float* y        = (float*)d_ws;               // NELEM
  float* accb     = y + NELEM;                  // NELEM
  float* kmem     = accb + NELEM;               // NELEM
  float* bias_cat = kmem + NELEM;               // NCAT
  _Float16* ys    = (_Float16*)(bias_cat + NCAT);  // NELEM (state for k1)
  _Float16* ts    = ys + NELEM;                    // NELEM (stage state)
  _Float16* Hh    = ts + NELEM;                    // BATCH*HID
  _Float16* WcatT = Hh + (size_t)BATCH * HID;      // NCAT*DIM
  _Float16* W2T   = WcatT + (size_t)NCAT * DIM;    // DIM*HID

  // ---- per-launch prep ----
  prep_wcat_k<<<(NCAT * DIM) / 256, 256, 0, stream>>>(W1, Wm, WcatT);
  prep_w2t_k<<<(DIM * HID) / 256, 256, 0, stream>>>(W2, W2T);
  prep_bias_k<<<(NCAT + 255) / 256, 256, 0, stream>>>(b1, bm, bias_cat);
  init_k<<<NELEM / 1024, 256, 0, stream>>>(x, y, out, ys);

  const dim3 g0(NCAT / 96, BATCH / 64);  // 24 x 32 = 768 blocks = 3/CU resident
  const dim3 g1(DIM / 96, BATCH / 32);   //  8 x 64 = 512 blocks = 2/CU resident

  auto gemm0 = [&](const _Float16* a) {
    gemm_k<0, 64, 96, 12><<<g0, 256, 0, stream>>>(
        a, WcatT, bias_cat, Hh, kmem, nullptr, nullptr, nullptr, nullptr,
        nullptr, nullptr, 0, 0.f, 0);
  };
  auto gemm1_stage = [&](int step, float hmul, int initf) {
    gemm_k<1, 32, 96, 24><<<g1, 256, 0, stream>>>(
        Hh, W2T, nullptr, nullptr, kmem, b2, y, accb, ts, nullptr, tg, step,
        hmul, initf);
  };
  auto gemm1_final = [&](int step, float* orow) {
    gemm_k<2, 32, 96, 24><<<g1, 256, 0, stream>>>(
        Hh, W2T, nullptr, nullptr, kmem, b2, y, accb, ys, orow, tg, step, 0.f,
        0);
  };

  for (int i = 0; i < T - 1; ++i) {
    gemm0(ys);  gemm1_stage(i, 0.5f, 1);   // k1
    gemm0(ts);  gemm1_stage(i, 0.5f, 0);   // k2
    gemm0(ts);  gemm1_stage(i, 1.0f, 0);   // k3
    gemm0(ts);  gemm1_final(i, out + (size_t)(i + 1) * NELEM);  // k4
  }
}